// Round 6
// baseline (948.742 us; speedup 1.0000x reference)
//
#include <hip/hip_runtime.h>
#include <cstdint>

#define Tt 1024
#define Hh 15
#define Ii 10
#define Oo 128
#define Bb 512

typedef float v4f __attribute__((ext_vector_type(4)));
typedef float v2f __attribute__((ext_vector_type(2)));

__device__ __forceinline__ float sigmoidf_(float x) {
    return 1.0f / (1.0f + __expf(-x));
}
__device__ __forceinline__ float tanhf_(float x) {
    return 1.0f - 2.0f / (__expf(2.0f * x) + 1.0f);
}

// DPP row-rotate of a float within the 16-lane row. j must be a literal.
#define ROT(x, j) __int_as_float(__builtin_amdgcn_update_dpp( \
    0, __float_as_int(x), 0x120 + (j), 0xF, 0xF, true))

#define ROTALL(dst, src)                                        \
    dst[0]  = (src);                                            \
    dst[1]  = ROT(src, 1);   dst[2]  = ROT(src, 2);             \
    dst[3]  = ROT(src, 3);   dst[4]  = ROT(src, 4);             \
    dst[5]  = ROT(src, 5);   dst[6]  = ROT(src, 6);             \
    dst[7]  = ROT(src, 7);   dst[8]  = ROT(src, 8);             \
    dst[9]  = ROT(src, 9);   dst[10] = ROT(src, 10);            \
    dst[11] = ROT(src, 11);  dst[12] = ROT(src, 12);            \
    dst[13] = ROT(src, 13);  dst[14] = ROT(src, 14);            \
    dst[15] = ROT(src, 15);

// Single fused kernel: 1 wave/block, 4 batch elems/wave, 16 lanes (one DPP
// row) per batch elem; lane u owns hidden unit u (u==15 inert in recur).
//
// Recurrence (bit-identical to the 527us passing kernel):
//   (W h)[u] = sum_j W[u][(u+dir*j)&15] * row_ror_j(h), k==15 taps zeroed.
//
// Projection fused into the recurrence's stall slots — R3 failed because a
// per-lane 128-float rotated W_out table blew the register allocator
// (VGPR stuck at 124 -> per-step table refetch, 516->1480 cyc/step).
// Fix: LDS h-transpose. Each lane writes its h to a 256B LDS tile; then
// ALL lanes see ALL 4 batches' h, so lane L owns only output rows
// {2L, 2L+1} (canonical order, 32-float table). Per step: 1 ds_write +
// 16 broadcast ds_read_b128 (uniform addr, conflict-free) + 64 pk-FMAs +
// 8 sigmoids + 4x8B coalesced nt-stores. DS ops are in-order within a
// wave; 1 wave/block -> no barrier needed.
__global__ __launch_bounds__(64, 1) void gru_fused(
    const float* __restrict__ feed, const float* __restrict__ h0,
    const float* __restrict__ W_ih, const float* __restrict__ W_hh,
    const float* __restrict__ b_ih, const float* __restrict__ b_hh,
    const float* __restrict__ W_out, const float* __restrict__ b_out,
    float* __restrict__ out)
{
    __shared__ float hlds[64];         // [4 batches][16 units]

    const int lane = threadIdx.x;      // 0..63
    const int g = lane >> 4;           // batch group = DPP row
    const int u = lane & 15;           // hidden unit (u==15 inert in recur)
    const int uu = (u < Hh) ? u : 0;
    const int b = blockIdx.x * 4 + g;

    // Probe DPP row_ror source direction once.
    int pr = __builtin_amdgcn_update_dpp(0, lane & 15, 0x121, 0xF, 0xF, true);
    int p0 = __builtin_amdgcn_readfirstlane(pr);
    const int dir = (p0 == 1) ? 1 : 15;   // 15*j == -j (mod 16)

    // Rotated recurrence weight tables (k==15 slots zeroed).
    float Wr[16], Wz[16], Wn[16];
    #pragma unroll
    for (int j = 0; j < 16; ++j) {
        int k = (uu + dir * j) & 15;
        bool ok = (k < Hh);
        int kk = ok ? k : 0;
        Wr[j] = ok ? W_hh[(uu         ) * Hh + kk] : 0.0f;
        Wz[j] = ok ? W_hh[(uu +     Hh) * Hh + kk] : 0.0f;
        Wn[j] = ok ? W_hh[(uu + 2 * Hh) * Hh + kk] : 0.0f;
    }

    // Projection weights: lane L owns output rows {2L, 2L+1}, canonical
    // order, k==15 tap zeroed. 32 floats total (v2f-packed for pk-FMA).
    const int o0 = lane * 2;
    float boA = b_out[o0], boB = b_out[o0 + 1];
    v2f wA[8], wB[8];
    #pragma unroll
    for (int jp = 0; jp < 8; ++jp) {
        int k0 = 2 * jp, k1 = 2 * jp + 1;
        float a0 = W_out[o0 * Hh + k0];
        float a1 = (k1 < Hh) ? W_out[o0 * Hh + k1] : 0.0f;
        float b0 = W_out[(o0 + 1) * Hh + k0];
        float b1 = (k1 < Hh) ? W_out[(o0 + 1) * Hh + k1] : 0.0f;
        wA[jp] = (v2f){a0, a1};
        wB[jp] = (v2f){b0, b1};
    }

    // Time-invariant input-gate constants.
    float cr = b_ih[uu]          + b_hh[uu];
    float cz = b_ih[uu + Hh]     + b_hh[uu + Hh];
    float cn = b_ih[uu + 2 * Hh];
    float bn = b_hh[uu + 2 * Hh];
    #pragma unroll
    for (int i = 0; i < Ii; ++i) {
        float x = feed[b * Ii + i];
        cr += x * W_ih[(uu         ) * Ii + i];
        cz += x * W_ih[(uu +     Hh) * Ii + i];
        cn += x * W_ih[(uu + 2 * Hh) * Ii + i];
    }

    float hcur = (u < Hh) ? h0[b * Hh + uu] : 0.0f;

    float hr[16];
    ROTALL(hr, hcur);

    float* obase = out + (size_t)(blockIdx.x * 4) * Oo + o0;

    for (int t = 0; t < Tt; ++t) {
        // ---- recurrence gates from hr (bit-identical to passing kernel) ----
        float ar[4] = {cr, 0.f, 0.f, 0.f};
        float az[4] = {cz, 0.f, 0.f, 0.f};
        float an[4] = {bn, 0.f, 0.f, 0.f};
        #pragma unroll
        for (int j = 0; j < 16; ++j) {
            ar[j & 3] += Wr[j] * hr[j];
            az[j & 3] += Wz[j] * hr[j];
            an[j & 3] += Wn[j] * hr[j];
        }
        float r = sigmoidf_((ar[0] + ar[1]) + (ar[2] + ar[3]));
        float z = sigmoidf_((az[0] + az[1]) + (az[2] + az[3]));
        float dn = (an[0] + an[1]) + (an[2] + an[3]);
        float n = tanhf_(cn + r * dn);
        float hnew = n + z * (hcur - n);

        // ---- publish h to LDS (lane15 writes finite junk; its tap is 0) ----
        hlds[g * 16 + u] = hnew;

        // ---- rotate hnew for the next step's gate chain ----
        ROTALL(hr, hnew);
        hcur = hnew;

        // ---- fused projection: lane L -> out[t][b0..b0+3][2L, 2L+1] ----
        // Independent of the next step's gate chain; fills its stall slots.
        #pragma unroll
        for (int g2 = 0; g2 < 4; ++g2) {
            const v4f* hp = (const v4f*)&hlds[g2 * 16];
            v4f HA = hp[0], HB = hp[1], HC = hp[2], HD = hp[3];
            v2f h2[8] = {
                (v2f){HA.x, HA.y}, (v2f){HA.z, HA.w},
                (v2f){HB.x, HB.y}, (v2f){HB.z, HB.w},
                (v2f){HC.x, HC.y}, (v2f){HC.z, HC.w},
                (v2f){HD.x, HD.y}, (v2f){HD.z, HD.w}};
            v2f aA = (v2f){boA, 0.0f};
            v2f aB = (v2f){boB, 0.0f};
            #pragma unroll
            for (int jp = 0; jp < 8; ++jp) {
                aA += wA[jp] * h2[jp];
                aB += wB[jp] * h2[jp];
            }
            v2f o2 = {sigmoidf_(aA.x + aA.y), sigmoidf_(aB.x + aB.y)};
            __builtin_nontemporal_store(
                o2, (v2f*)(obase + (size_t)g2 * Oo));
        }
        obase += (size_t)Bb * Oo;
    }
}

extern "C" void kernel_launch(void* const* d_in, const int* in_sizes, int n_in,
                              void* d_out, int out_size, void* d_ws, size_t ws_size,
                              hipStream_t stream) {
    const float* feed  = (const float*)d_in[0];
    const float* h0    = (const float*)d_in[1];
    const float* W_ih  = (const float*)d_in[2];
    const float* W_hh  = (const float*)d_in[3];
    const float* b_ih  = (const float*)d_in[4];
    const float* b_hh  = (const float*)d_in[5];
    const float* W_out = (const float*)d_in[6];
    const float* b_out = (const float*)d_in[7];
    float* out = (float*)d_out;
    (void)d_ws;

    gru_fused<<<Bb / 4, 64, 0, stream>>>(
        feed, h0, W_ih, W_hh, b_ih, b_hh, W_out, b_out, out);
}

// Round 8
// 888.485 us; speedup vs baseline: 1.0678x; 1.0678x over previous
//
#include <hip/hip_runtime.h>
#include <cstdint>

#define Tt 1024
#define Hh 15
#define Ii 10
#define Oo 128
#define Bb 512

typedef float v4f __attribute__((ext_vector_type(4)));
typedef float v2f __attribute__((ext_vector_type(2)));

__device__ __forceinline__ float sigmoidf_(float x) {
    return 1.0f / (1.0f + __expf(-x));
}
__device__ __forceinline__ float tanhf_(float x) {
    return 1.0f - 2.0f / (__expf(2.0f * x) + 1.0f);
}

// DPP row-rotate of a float within the 16-lane row. j must be a literal.
#define ROT(x, j) __int_as_float(__builtin_amdgcn_update_dpp( \
    0, __float_as_int(x), 0x120 + (j), 0xF, 0xF, true))

#define ROTALL(dst, src)                                        \
    dst[0]  = (src);                                            \
    dst[1]  = ROT(src, 1);   dst[2]  = ROT(src, 2);             \
    dst[3]  = ROT(src, 3);   dst[4]  = ROT(src, 4);             \
    dst[5]  = ROT(src, 5);   dst[6]  = ROT(src, 6);             \
    dst[7]  = ROT(src, 7);   dst[8]  = ROT(src, 8);             \
    dst[9]  = ROT(src, 9);   dst[10] = ROT(src, 10);            \
    dst[11] = ROT(src, 11);  dst[12] = ROT(src, 12);            \
    dst[13] = ROT(src, 13);  dst[14] = ROT(src, 14);            \
    dst[15] = ROT(src, 15);

// Fused GRU, SOFTWARE-PIPELINED one step deep.
//
// R6 post-mortem: proj(t) consumed hnew(t) = the END of step t's dependency
// chain -> structurally impossible to overlap; step time was the serial sum
// gates(516cy) + LDS round-trip + proj (1709cy total, VALUBusy ~10%).
// Fix: iteration t computes gates(t) AND projects h(t-1) (already in LDS
// from last iteration). The two streams share no values -> same basic
// block, scheduler fills the gate chain's stall slots with proj work.
// hlds write of h(t) sits program-order AFTER proj's reads of h(t-1)
// (in-order DS pipe + may-alias => read-before-write preserved).
//
// Recurrence math bit-identical to the 527us baseline. Projection: lane L
// owns output rows {2L, 2L+1} canonically (32-float weight table), h
// broadcast via 256B LDS tile (uniform-address ds_read_b128, conflict-free).
__global__ __launch_bounds__(64, 1) void gru_fused(
    const float* __restrict__ feed, const float* __restrict__ h0,
    const float* __restrict__ W_ih, const float* __restrict__ W_hh,
    const float* __restrict__ b_ih, const float* __restrict__ b_hh,
    const float* __restrict__ W_out, const float* __restrict__ b_out,
    float* __restrict__ out)
{
    __shared__ float hlds[64];         // [4 batches][16 units]

    const int lane = threadIdx.x;      // 0..63
    const int g = lane >> 4;           // batch group = DPP row
    const int u = lane & 15;           // hidden unit (u==15 inert in recur)
    const int uu = (u < Hh) ? u : 0;
    const int b = blockIdx.x * 4 + g;

    // Probe DPP row_ror source direction once.
    int pr = __builtin_amdgcn_update_dpp(0, lane & 15, 0x121, 0xF, 0xF, true);
    int p0 = __builtin_amdgcn_readfirstlane(pr);
    const int dir = (p0 == 1) ? 1 : 15;   // 15*j == -j (mod 16)

    // Rotated recurrence weight tables (k==15 slots zeroed).
    float Wr[16], Wz[16], Wn[16];
    #pragma unroll
    for (int j = 0; j < 16; ++j) {
        int k = (uu + dir * j) & 15;
        bool ok = (k < Hh);
        int kk = ok ? k : 0;
        Wr[j] = ok ? W_hh[(uu         ) * Hh + kk] : 0.0f;
        Wz[j] = ok ? W_hh[(uu +     Hh) * Hh + kk] : 0.0f;
        Wn[j] = ok ? W_hh[(uu + 2 * Hh) * Hh + kk] : 0.0f;
    }

    // Projection weights: lane L owns output rows {2L, 2L+1}, canonical
    // order, k==15 tap zeroed (hlds slot 15 of each group is junk).
    const int o0 = lane * 2;
    float boA = b_out[o0], boB = b_out[o0 + 1];
    v2f wA[8], wB[8];
    #pragma unroll
    for (int jp = 0; jp < 8; ++jp) {
        int k0 = 2 * jp, k1 = 2 * jp + 1;
        float a0 = W_out[o0 * Hh + k0];
        float a1 = (k1 < Hh) ? W_out[o0 * Hh + k1] : 0.0f;
        float b0 = W_out[(o0 + 1) * Hh + k0];
        float b1 = (k1 < Hh) ? W_out[(o0 + 1) * Hh + k1] : 0.0f;
        wA[jp] = (v2f){a0, a1};
        wB[jp] = (v2f){b0, b1};
    }

    // Time-invariant input-gate constants.
    float cr = b_ih[uu]          + b_hh[uu];
    float cz = b_ih[uu + Hh]     + b_hh[uu + Hh];
    float cn = b_ih[uu + 2 * Hh];
    float bn = b_hh[uu + 2 * Hh];
    #pragma unroll
    for (int i = 0; i < Ii; ++i) {
        float x = feed[b * Ii + i];
        cr += x * W_ih[(uu         ) * Ii + i];
        cz += x * W_ih[(uu +     Hh) * Ii + i];
        cn += x * W_ih[(uu + 2 * Hh) * Ii + i];
    }

    float hcur = (u < Hh) ? h0[b * Hh + uu] : 0.0f;

    float hr[16];
    ROTALL(hr, hcur);

    // One GRU gate step: hr/hcur -> hnew. Bit-identical to baseline.
    auto gate_step = [&]() -> float {
        float ar[4] = {cr, 0.f, 0.f, 0.f};
        float az[4] = {cz, 0.f, 0.f, 0.f};
        float an[4] = {bn, 0.f, 0.f, 0.f};
        #pragma unroll
        for (int j = 0; j < 16; ++j) {
            ar[j & 3] += Wr[j] * hr[j];
            az[j & 3] += Wz[j] * hr[j];
            an[j & 3] += Wn[j] * hr[j];
        }
        float r = sigmoidf_((ar[0] + ar[1]) + (ar[2] + ar[3]));
        float z = sigmoidf_((az[0] + az[1]) + (az[2] + az[3]));
        float dn = (an[0] + an[1]) + (an[2] + an[3]);
        float n = tanhf_(cn + r * dn);
        return n + z * (hcur - n);
    };

    // Project the h currently in hlds to optr (one time-row of out).
    auto proj_step = [&](float* optr) {
        #pragma unroll
        for (int g2 = 0; g2 < 4; ++g2) {
            const v4f* hp = (const v4f*)&hlds[g2 * 16];
            v4f HA = hp[0], HB = hp[1], HC = hp[2], HD = hp[3];
            v2f h2[8] = {
                (v2f){HA.x, HA.y}, (v2f){HA.z, HA.w},
                (v2f){HB.x, HB.y}, (v2f){HB.z, HB.w},
                (v2f){HC.x, HC.y}, (v2f){HC.z, HC.w},
                (v2f){HD.x, HD.y}, (v2f){HD.z, HD.w}};
            v2f aA = (v2f){boA, 0.0f};
            v2f aB = (v2f){boB, 0.0f};
            #pragma unroll
            for (int jp = 0; jp < 8; ++jp) {
                aA += wA[jp] * h2[jp];
                aB += wB[jp] * h2[jp];
            }
            v2f o2 = {sigmoidf_(aA.x + aA.y), sigmoidf_(aB.x + aB.y)};
            __builtin_nontemporal_store(o2, (v2f*)(optr + (size_t)g2 * Oo));
        }
    };

    float* obase = out + (size_t)(blockIdx.x * 4) * Oo + o0;

    // ---- step 0 (peeled): gates only, publish h(0) ----
    {
        float hnew = gate_step();
        hlds[g * 16 + u] = hnew;       // lane15 junk; its proj tap is zeroed
        ROTALL(hr, hnew);
        hcur = hnew;
    }

    // ---- pipelined steady state: gates(t) || proj(t-1) ----
    for (int t = 1; t < Tt; ++t) {
        float hnew = gate_step();      // long chain; independent of proj below
        proj_step(obase);              // reads hlds = h(t-1), fills stall slots
        obase += (size_t)Bb * Oo;
        hlds[g * 16 + u] = hnew;       // publish h(t) AFTER proj's reads
        ROTALL(hr, hnew);
        hcur = hnew;
    }

    // ---- epilogue: project h(Tt-1) ----
    proj_step(obase);
}

extern "C" void kernel_launch(void* const* d_in, const int* in_sizes, int n_in,
                              void* d_out, int out_size, void* d_ws, size_t ws_size,
                              hipStream_t stream) {
    const float* feed  = (const float*)d_in[0];
    const float* h0    = (const float*)d_in[1];
    const float* W_ih  = (const float*)d_in[2];
    const float* W_hh  = (const float*)d_in[3];
    const float* b_ih  = (const float*)d_in[4];
    const float* b_hh  = (const float*)d_in[5];
    const float* W_out = (const float*)d_in[6];
    const float* b_out = (const float*)d_in[7];
    float* out = (float*)d_out;
    (void)d_ws;

    gru_fused<<<Bb / 4, 64, 0, stream>>>(
        feed, h0, W_ih, W_hh, b_ih, b_hh, W_out, b_out, out);
}

// Round 13
// 553.254 us; speedup vs baseline: 1.7148x; 1.6059x over previous
//
#include <hip/hip_runtime.h>
#include <cstdint>

#define Tt 1024
#define Hh 15
#define Ii 10
#define Oo 128
#define Bb 512

typedef float v4f __attribute__((ext_vector_type(4)));

__device__ __forceinline__ float sigmoidf_(float x) {
    return 1.0f / (1.0f + __expf(-x));
}
__device__ __forceinline__ float tanhf_(float x) {
    return 1.0f - 2.0f / (__expf(2.0f * x) + 1.0f);
}

// DPP row-rotate of a float within the 16-lane row. j must be a literal.
#define ROT(x, j) __int_as_float(__builtin_amdgcn_update_dpp( \
    0, __float_as_int(x), 0x120 + (j), 0xF, 0xF, true))

// Kernel A: sequential recurrence. 1 wave/block, 4 batch elems/wave,
// 16 lanes (one DPP row) per batch elem; lane u owns hidden unit u.
//
// R9 change vs the 527us baseline: the 48-float rotated weight tables
// (Wr/Wz/Wn) move from VGPRs to LDS. Rationale: baseline VGPR_Count=56 <
// the ~86-register live set -> the allocator re-loaded the tables from
// global/L1 EVERY STEP (~48 loads + addr VALU + vmcnt waits ~= 300 of the
// 516 cyc/step). LDS layout [gate][u][20] (stride 20 floats = 16B-aligned
// rows; bank starts (u*20)%32 uniform 2-way = free; the 4 batch groups
// share addresses = broadcast). Per step: 12 ds_read_b128, issue 24 cyc.
// Gate math and summation order bit-identical to baseline.
__global__ __launch_bounds__(64, 1) void gru_recur(
    const float* __restrict__ feed, const float* __restrict__ h0,
    const float* __restrict__ W_ih, const float* __restrict__ W_hh,
    const float* __restrict__ b_ih, const float* __restrict__ b_hh,
    float* __restrict__ hs)
{
    __shared__ float Wl[3][16][20];    // [gate][unit u][tap j], padded row

    const int lane = threadIdx.x;      // 0..63
    const int g = lane >> 4;           // batch group = DPP row
    const int u = lane & 15;           // hidden unit (u==15 inert)
    const int uu = (u < Hh) ? u : 0;
    const int b = blockIdx.x * 4 + g;

    // Probe DPP row_ror source direction once.
    int pr = __builtin_amdgcn_update_dpp(0, lane & 15, 0x121, 0xF, 0xF, true);
    int p0 = __builtin_amdgcn_readfirstlane(pr);
    const int dir = (p0 == 1) ? 1 : 15;   // 15*j == -j (mod 16)

    // Cooperative fill of the rotated weight tables. Values identical to
    // the baseline's per-lane tables; u==15 rows are all-zero (junk lane).
    for (int idx = lane; idx < 3 * 16 * 16; idx += 64) {
        int gate = idx >> 8;           // 0..2
        int rem  = idx & 255;
        int uw   = rem >> 4;           // 0..15
        int j    = rem & 15;           // 0..15
        int k    = (uw + dir * j) & 15;
        float v  = 0.0f;
        if (uw < Hh && k < Hh)
            v = W_hh[(uw + gate * Hh) * Hh + k];
        Wl[gate][uw][j] = v;
    }
    __syncthreads();

    // Loop-invariant LDS row pointers (16B-aligned: u*80 bytes).
    const v4f* wr4 = (const v4f*)&Wl[0][u][0];
    const v4f* wz4 = (const v4f*)&Wl[1][u][0];
    const v4f* wn4 = (const v4f*)&Wl[2][u][0];

    // Time-invariant input-gate constants (gi = x@W_ih.T + b_ih; b_hh r,z
    // folded; b_hh n-part seeds the n-dot).
    float cr = b_ih[uu]          + b_hh[uu];
    float cz = b_ih[uu + Hh]     + b_hh[uu + Hh];
    float cn = b_ih[uu + 2 * Hh];
    float bn = b_hh[uu + 2 * Hh];
    #pragma unroll
    for (int i = 0; i < Ii; ++i) {
        float x = feed[b * Ii + i];
        cr += x * W_ih[(uu         ) * Ii + i];
        cz += x * W_ih[(uu +     Hh) * Ii + i];
        cn += x * W_ih[(uu + 2 * Hh) * Ii + i];
    }

    float hcur = (u < Hh) ? h0[b * Hh + uu] : 0.0f;
    size_t off = (size_t)b * 16 + u;

    for (int t = 0; t < Tt; ++t) {
        float hr[16];
        hr[0]  = hcur;
        hr[1]  = ROT(hcur, 1);   hr[2]  = ROT(hcur, 2);
        hr[3]  = ROT(hcur, 3);   hr[4]  = ROT(hcur, 4);
        hr[5]  = ROT(hcur, 5);   hr[6]  = ROT(hcur, 6);
        hr[7]  = ROT(hcur, 7);   hr[8]  = ROT(hcur, 8);
        hr[9]  = ROT(hcur, 9);   hr[10] = ROT(hcur, 10);
        hr[11] = ROT(hcur, 11);  hr[12] = ROT(hcur, 12);
        hr[13] = ROT(hcur, 13);  hr[14] = ROT(hcur, 14);
        hr[15] = ROT(hcur, 15);

        // 12 ds_read_b128: whole weight set for this step (transient regs).
        v4f WR[4] = {wr4[0], wr4[1], wr4[2], wr4[3]};
        v4f WZ[4] = {wz4[0], wz4[1], wz4[2], wz4[3]};
        v4f WN[4] = {wn4[0], wn4[1], wn4[2], wn4[3]};

        // 4-way split accumulators per gate (same order as baseline).
        float ar[4] = {cr, 0.f, 0.f, 0.f};
        float az[4] = {cz, 0.f, 0.f, 0.f};
        float an[4] = {bn, 0.f, 0.f, 0.f};
        #pragma unroll
        for (int j = 0; j < 16; ++j) {
            ar[j & 3] += WR[j >> 2][j & 3] * hr[j];
            az[j & 3] += WZ[j >> 2][j & 3] * hr[j];
            an[j & 3] += WN[j >> 2][j & 3] * hr[j];
        }
        float r = sigmoidf_((ar[0] + ar[1]) + (ar[2] + ar[3]));
        float z = sigmoidf_((az[0] + az[1]) + (az[2] + az[3]));
        float dn = (an[0] + an[1]) + (an[2] + an[3]);
        float n = tanhf_(cn + r * dn);
        float hnew = n + z * (hcur - n);

        hs[off] = hnew;            // lane15 writes pad slot (finite junk)
        off += (size_t)Bb * 16;
        hcur = hnew;
    }
}

__device__ __forceinline__ v4f ntload4(const float* p) {
    return __builtin_nontemporal_load((const v4f*)p);
}

// Kernel B: out[p,o] = sigmoid(hs[p,:] . W_out[o,:] + b_out[o]).
// 2-deep software pipeline; nontemporal streaming loads/stores.
// (Verbatim from the 527us baseline — measured ~88us, ~3.4 TB/s.)
__global__ __launch_bounds__(256) void gru_proj(
    const float* __restrict__ hs, const float* __restrict__ W_out,
    const float* __restrict__ b_out, float* __restrict__ out)
{
    const int q  = threadIdx.x & 31;   // o-quad
    const int gg = threadIdx.x >> 5;   // p-slot within block (0..7)
    const int o0 = q * 4;

    float w[4][Hh];
    float bo[4];
    #pragma unroll
    for (int j = 0; j < 4; ++j) {
        bo[j] = b_out[o0 + j];
        #pragma unroll
        for (int k = 0; k < Hh; ++k) w[j][k] = W_out[(o0 + j) * Hh + k];
    }

    const int P = Tt * Bb;
    const int stride = gridDim.x * 8;
    int p = blockIdx.x * 8 + gg;
    if (p >= P) return;

    const float* hp = hs + (size_t)p * 16;
    v4f A = ntload4(hp), B_ = ntload4(hp + 4), C = ntload4(hp + 8), D = ntload4(hp + 12);

    while (true) {
        int pn = p + stride;
        bool more = pn < P;
        const float* hpn = hs + (size_t)(more ? pn : p) * 16;
        v4f A2 = ntload4(hpn), B2 = ntload4(hpn + 4),
            C2 = ntload4(hpn + 8), D2 = ntload4(hpn + 12);

        float h[Hh] = {A.x, A.y, A.z, A.w, B_.x, B_.y, B_.z, B_.w,
                       C.x, C.y, C.z, C.w, D.x, D.y, D.z};
        float acc[4];
        #pragma unroll
        for (int j = 0; j < 4; ++j) {
            float s0 = bo[j], s1 = 0.f;
            #pragma unroll
            for (int k = 0; k < Hh; k += 2) s0 += h[k] * w[j][k];
            #pragma unroll
            for (int k = 1; k < Hh; k += 2) s1 += h[k] * w[j][k];
            acc[j] = sigmoidf_(s0 + s1);
        }
        v4f res = {acc[0], acc[1], acc[2], acc[3]};
        __builtin_nontemporal_store(res, (v4f*)(out + (size_t)p * (size_t)Oo + o0));

        if (!more) break;
        p = pn; A = A2; B_ = B2; C = C2; D = D2;
    }
}

extern "C" void kernel_launch(void* const* d_in, const int* in_sizes, int n_in,
                              void* d_out, int out_size, void* d_ws, size_t ws_size,
                              hipStream_t stream) {
    const float* feed  = (const float*)d_in[0];
    const float* h0    = (const float*)d_in[1];
    const float* W_ih  = (const float*)d_in[2];
    const float* W_hh  = (const float*)d_in[3];
    const float* b_ih  = (const float*)d_in[4];
    const float* b_hh  = (const float*)d_in[5];
    const float* W_out = (const float*)d_in[6];
    const float* b_out = (const float*)d_in[7];
    float* out = (float*)d_out;
    float* hs  = (float*)d_ws;   // [T][B][16] floats = 33.5 MB

    gru_recur<<<Bb / 4, 64, 0, stream>>>(feed, h0, W_ih, W_hh, b_ih, b_hh, hs);
    gru_proj<<<2048, 256, 0, stream>>>(hs, W_out, b_out, out);
}